// Round 5
// baseline (116.836 us; speedup 1.0000x reference)
//
#include <hip/hip_runtime.h>

// LoFTR2Tensor: jagged -> padded dense scatter, sorted batch_indexes.
// Fast path: speculatively guess batch g = i0/L (the equal-count layout) and
// PROVE start[g] == g*L with 4 independent O(1) loads (sorted input =>
// bidx[g*L-1]==g-1 && bidx[g*L]==g  <=>  lower_bound(g)==g*L). In the fast
// path base == i0, so the kernel is a pure identity float4 copy with
// nontemporal hints (streams >> L3, zero reuse). General jagged inputs fall
// back to a per-point binary search (mode="drop" semantics preserved).
//
// CHUNK=4096 (vs 2048 in r4): halves block count -> halves per-block cold
// verification rounds, doubles per-thread outstanding loads (10 -> 20).

#define CHUNK 4096   // points per block
#define BLOCK 256

typedef float vfloat4 __attribute__((ext_vector_type(4)));  // native vector:
// __builtin_nontemporal_* rejects HIP's class-type float4.

__global__ __launch_bounds__(BLOCK)
void loftr_copy(const float* __restrict__ kp0,
                const float* __restrict__ kp1,
                const float* __restrict__ conf,
                const int* __restrict__ bidx,
                const int* __restrict__ mp_p,
                float* __restrict__ out,
                long long n, long long M /* = num_batches*max_points */) {
    const long long i0 = (long long)blockIdx.x * CHUNK;
    if (i0 >= n) return;
    const long long L = *mp_p;               // wave-uniform scalar
    const long long iend = i0 + CHUNK;

    float* __restrict__ src = out;            // (B, L, 2)
    float* __restrict__ tgt = out + 2 * M;    // (B, L, 2)
    float* __restrict__ sco = out + 4 * M;    // (B, L)

    // ---- O(1) fast-path verification (all wave-uniform; no LDS, no barrier)
    bool fast = false;
    if (iend <= n && L > 0) {
        const long long g = i0 / L;
        const long long pos0 = i0 - g * L;
        if (pos0 + CHUNK <= L) {
            const int bi0 = bidx[i0];
            const int bi1 = bidx[iend - 1];
            bool ok = (bi0 == (int)g) && (bi1 == (int)g);
            if (ok && g > 0) {
                ok = (bidx[g * L] == (int)g) && (bidx[g * L - 1] == (int)(g - 1));
            }
            fast = ok;   // proven: start[g] == g*L, whole chunk in batch g
        }
    }

    if (fast) {
        // base = g*L + (i0 - g*L) = i0 -> identity copy, 16B aligned both sides.
        const vfloat4* __restrict__ a4 = reinterpret_cast<const vfloat4*>(kp0 + 2 * i0);
        const vfloat4* __restrict__ b4 = reinterpret_cast<const vfloat4*>(kp1 + 2 * i0);
        const vfloat4* __restrict__ c4 = reinterpret_cast<const vfloat4*>(conf + i0);
        vfloat4* __restrict__ s4 = reinterpret_cast<vfloat4*>(src + 2 * i0);
        vfloat4* __restrict__ t4 = reinterpret_cast<vfloat4*>(tgt + 2 * i0);
        vfloat4* __restrict__ o4 = reinterpret_cast<vfloat4*>(sco + i0);
        const int t = threadIdx.x;

        // kp streams: 2*CHUNK/4 = 2048 float4 each -> 8/thread; conf: 4/thread.
        // All 20 loads independent -> deep MLP, perfectly coalesced.
        vfloat4 ra[8], rb[8], rc[4];
#pragma unroll
        for (int k = 0; k < 8; ++k) ra[k] = __builtin_nontemporal_load(a4 + t + 256 * k);
#pragma unroll
        for (int k = 0; k < 8; ++k) rb[k] = __builtin_nontemporal_load(b4 + t + 256 * k);
#pragma unroll
        for (int k = 0; k < 4; ++k) rc[k] = __builtin_nontemporal_load(c4 + t + 256 * k);

#pragma unroll
        for (int k = 0; k < 8; ++k) __builtin_nontemporal_store(ra[k], s4 + t + 256 * k);
#pragma unroll
        for (int k = 0; k < 8; ++k) __builtin_nontemporal_store(rb[k], t4 + t + 256 * k);
#pragma unroll
        for (int k = 0; k < 4; ++k) __builtin_nontemporal_store(rc[k], o4 + t + 256 * k);
    } else {
        // General sorted-jagged fallback (boundary/tail/non-uniform counts).
        for (long long i = i0 + threadIdx.x; i < iend && i < n; i += BLOCK) {
            const int b = bidx[i];
            long long lo = 0, hi = i;
            while (lo < hi) {
                long long mid = (lo + hi) >> 1;
                if (bidx[mid] < b) lo = mid + 1; else hi = mid;
            }
            const long long pos = i - lo;
            if (pos < L) {   // mode="drop"
                const long long e = (long long)b * L + pos;
                src[2 * e]     = kp0[2 * i];
                src[2 * e + 1] = kp0[2 * i + 1];
                tgt[2 * e]     = kp1[2 * i];
                tgt[2 * e + 1] = kp1[2 * i + 1];
                sco[e]         = conf[i];
            }
        }
    }
}

extern "C" void kernel_launch(void* const* d_in, const int* in_sizes, int n_in,
                              void* d_out, int out_size, void* d_ws, size_t ws_size,
                              hipStream_t stream) {
    const float* kp0  = (const float*)d_in[0];
    const float* kp1  = (const float*)d_in[1];
    const float* conf = (const float*)d_in[2];
    const int* bidx   = (const int*)d_in[3];
    const int* mp_p   = (const int*)d_in[5];   // max_points (device scalar)

    const long long n = in_sizes[2];           // total points
    const long long M = (long long)out_size / 5;  // num_batches * max_points

    const int grid = (int)((n + CHUNK - 1) / CHUNK);
    loftr_copy<<<grid, BLOCK, 0, stream>>>(kp0, kp1, conf, bidx, mp_p,
                                           (float*)d_out, n, M);
}